// Round 3
// baseline (422.177 us; speedup 1.0000x reference)
//
#include <hip/hip_runtime.h>

namespace {
constexpr int kB = 16;
constexpr int kN = 131072;            // 2^17
constexpr int kNLog = 17;
constexpr int kCMid = 128;
constexpr int kCOut = 16;
constexpr int kCells32Log = 15;       // 32^3
constexpr int kCells64Log = 18;       // 64^3
constexpr int kCells32 = 1 << kCells32Log;
constexpr int kCells64 = 1 << kCells64Log;
constexpr long kOut32Elems = (long)kB * kCOut * kCells32;
}  // namespace

// ---------------------------------------------------------------------------
// Stage packed weights into ws: W1p[k][4] = (w0,w1,w2,b1k); W2t[k][16].
// Contiguous float4 rows -> uniform-address broadcast loads in hot loops.
// ---------------------------------------------------------------------------
__global__ __launch_bounds__(256) void pack_weights(
    const float* __restrict__ W1, const float* __restrict__ b1,
    const float* __restrict__ W2,
    float* __restrict__ W1p, float* __restrict__ W2t)
{
    const int t = threadIdx.x;
    for (int k = t; k < kCMid; k += 256) {
        W1p[k * 4 + 0] = W1[k * 3 + 0];
        W1p[k * 4 + 1] = W1[k * 3 + 1];
        W1p[k * 4 + 2] = W1[k * 3 + 2];
        W1p[k * 4 + 3] = b1[k];
    }
    for (int idx = t; idx < kCOut * kCMid; idx += 256) {
        const int c = idx >> 7;        // idx / 128
        const int k = idx & 127;
        W2t[k * kCOut + c] = W2[idx];
    }
}

// ---------------------------------------------------------------------------
// Scatter only: per permuted position (b,i): j=perm, gather x[b,j], compute
// both cell ids, atomicMax(winner, i+1). No MLP, no feat store.
// Cell math uses __fmul_rn/__fadd_rn (no FMA contraction) so truncation
// boundaries match numpy's mul-then-add exactly.
// ---------------------------------------------------------------------------
__global__ __launch_bounds__(256, 4) void scatter_winners(
    const float* __restrict__ x,
    const int* __restrict__ perm,
    unsigned int* __restrict__ win32, unsigned int* __restrict__ win64)
{
    const long gid = (long)blockIdx.x * 256 + threadIdx.x;  // over B*N
    const int b = (int)(gid >> kNLog);
    const int i = (int)(gid & (kN - 1));
    const int j = perm[gid];

    const float* xp = x + ((long)b * kN + j) * 3;
    const float v0 = xp[0], v1 = xp[1], v2 = xp[2];

    const int ix32 = (int)fminf(fmaxf(__fadd_rn(__fmul_rn(v0, 32.0f), 16.5f), 0.0f), 31.0f);
    const int iy32 = (int)fminf(fmaxf(__fadd_rn(__fmul_rn(v1, 32.0f), 16.5f), 0.0f), 31.0f);
    const int iz32 = (int)fminf(fmaxf(__fadd_rn(__fmul_rn(v2, 32.0f), 16.5f), 0.0f), 31.0f);
    const int ix64 = (int)fminf(fmaxf(__fadd_rn(__fmul_rn(v0, 64.0f), 32.5f), 0.0f), 63.0f);
    const int iy64 = (int)fminf(fmaxf(__fadd_rn(__fmul_rn(v1, 64.0f), 32.5f), 0.0f), 63.0f);
    const int iz64 = (int)fminf(fmaxf(__fadd_rn(__fmul_rn(v2, 64.0f), 32.5f), 0.0f), 63.0f);

    const unsigned int pri = (unsigned int)(i + 1);
    atomicMax(&win32[b * kCells32 + (ix32 * 32 + iy32) * 32 + iz32], pri);
    atomicMax(&win64[b * kCells64 + (ix64 * 64 + iy64) * 64 + iz64], pri);
}

// ---------------------------------------------------------------------------
// Per-cell gather + MLP recompute: read winner i, j=perm[b,i], x[b,j],
// recompute feat (2560 FMA), write 16 channels (zeros if empty). Rewrites
// the full output every call (deterministic, no reliance on poison state).
// Weight reads are loop-uniform float4s from the 10KB packed block (L1-hit).
// ---------------------------------------------------------------------------
template <int CLOG>
__global__ __launch_bounds__(256, 4) void gather_cells(
    const unsigned int* __restrict__ win,
    const int* __restrict__ perm,
    const float* __restrict__ x,
    const float* __restrict__ W1p, const float* __restrict__ W2t,
    const float* __restrict__ b2,
    float* __restrict__ out)
{
    constexpr int cells = 1 << CLOG;
    const long gid = (long)blockIdx.x * 256 + threadIdx.x;  // over B*cells
    const int b = (int)(gid >> CLOG);
    const int cell = (int)(gid & (cells - 1));
    const unsigned int w = win[gid];

    float v[kCOut];
    #pragma unroll
    for (int c = 0; c < kCOut; ++c) v[c] = 0.0f;

    if (w != 0u) {
        const int i = (int)(w - 1u);
        const int j = perm[((long)b << kNLog) + i];
        const float* xp = x + ((long)b * kN + j) * 3;
        const float v0 = xp[0], v1 = xp[1], v2 = xp[2];
        const float4* __restrict__ w1v = (const float4*)W1p;
        const float4* __restrict__ w2v = (const float4*)W2t;
        #pragma unroll 4
        for (int k = 0; k < kCMid; ++k) {
            const float4 w1 = w1v[k];
            const float h = fmaxf(fmaf(w1.x, v0, fmaf(w1.y, v1, fmaf(w1.z, v2, w1.w))), 0.0f);
            #pragma unroll
            for (int q = 0; q < 4; ++q) {
                const float4 wq = w2v[k * 4 + q];
                v[4 * q + 0] = fmaf(wq.x, h, v[4 * q + 0]);
                v[4 * q + 1] = fmaf(wq.y, h, v[4 * q + 1]);
                v[4 * q + 2] = fmaf(wq.z, h, v[4 * q + 2]);
                v[4 * q + 3] = fmaf(wq.w, h, v[4 * q + 3]);
            }
        }
        #pragma unroll
        for (int c = 0; c < kCOut; ++c) v[c] += b2[c];
    }

    float* op = out + (((long)b * kCOut) << CLOG) + cell;
    #pragma unroll
    for (int c = 0; c < kCOut; ++c) op[(long)c << CLOG] = v[c];
}

extern "C" void kernel_launch(void* const* d_in, const int* in_sizes, int n_in,
                              void* d_out, int out_size, void* d_ws, size_t ws_size,
                              hipStream_t stream)
{
    const float* x  = (const float*)d_in[0];
    const float* W1 = (const float*)d_in[1];
    const float* b1 = (const float*)d_in[2];
    const float* W2 = (const float*)d_in[3];
    const float* b2 = (const float*)d_in[4];
    const int* perm = (const int*)d_in[5];

    float* out32 = (float*)d_out;
    float* out64 = out32 + kOut32Elems;

    // ws layout: [W1p 2KB][W2t 8KB][pad->16KB][win32][win64]
    float* W1p = (float*)d_ws;
    float* W2t = W1p + kCMid * 4;
    unsigned int* win32 = (unsigned int*)((char*)d_ws + 16384);
    unsigned int* win64 = win32 + (size_t)kB * kCells32;
    const size_t winnerBytes = (size_t)kB * (kCells32 + kCells64) * sizeof(unsigned int);

    hipMemsetAsync(win32, 0, winnerBytes, stream);
    pack_weights<<<1, 256, 0, stream>>>(W1, b1, W2, W1p, W2t);

    const int nPtsBlocks = (int)(((long)kB * kN) / 256);        // 8192
    const int n32Blocks  = (int)(((long)kB * kCells32) / 256);  // 2048
    const int n64Blocks  = (int)(((long)kB * kCells64) / 256);  // 16384
    dim3 blk(256);

    scatter_winners<<<nPtsBlocks, blk, 0, stream>>>(x, perm, win32, win64);
    gather_cells<kCells32Log><<<n32Blocks, blk, 0, stream>>>(
        win32, perm, x, W1p, W2t, b2, out32);
    gather_cells<kCells64Log><<<n64Blocks, blk, 0, stream>>>(
        win64, perm, x, W1p, W2t, b2, out64);
}

// Round 4
// 294.480 us; speedup vs baseline: 1.4336x; 1.4336x over previous
//
#include <hip/hip_runtime.h>

namespace {
constexpr int kB = 16;
constexpr int kN = 131072;            // 2^17
constexpr int kNLog = 17;
constexpr int kCMid = 128;
constexpr int kCOut = 16;
constexpr int kCells32Log = 15;       // 32^3
constexpr int kCells64Log = 18;       // 64^3
constexpr int kCells32 = 1 << kCells32Log;
constexpr int kCells64 = 1 << kCells64Log;
constexpr long kOut32Elems = (long)kB * kCOut * kCells32;
}  // namespace

union F32U { float f; unsigned int u; };

__device__ inline unsigned int packbf2(float lo, float hi) {
    // RNE-round both to bf16, pack (hi<<16)|lo
    F32U a; a.f = lo;
    F32U b; b.f = hi;
    unsigned int ra = (a.u + 0x7FFFu + ((a.u >> 16) & 1u)) >> 16;
    unsigned int rb = (b.u + 0x7FFFu + ((b.u >> 16) & 1u)) >> 16;
    return (rb << 16) | (ra & 0xFFFFu);
}

__device__ inline float bf_lo(unsigned int p) { F32U v; v.u = p << 16; return v.f; }
__device__ inline float bf_hi(unsigned int p) { F32U v; v.u = p & 0xFFFF0000u; return v.f; }

// ---------------------------------------------------------------------------
// Stage packed weights: W1p[k][4] = (w0,w1,w2,b1k); W2t[k][16] (transposed).
// Loop-uniform float4 reads in hot loops -> compiler emits s_load broadcasts
// (verified R3: VGPR=16/SGPR=96 in the MLP loop).
// ---------------------------------------------------------------------------
__global__ __launch_bounds__(256) void pack_weights(
    const float* __restrict__ W1, const float* __restrict__ b1,
    const float* __restrict__ W2,
    float* __restrict__ W1p, float* __restrict__ W2t)
{
    const int t = threadIdx.x;
    for (int k = t; k < kCMid; k += 256) {
        W1p[k * 4 + 0] = W1[k * 3 + 0];
        W1p[k * 4 + 1] = W1[k * 3 + 1];
        W1p[k * 4 + 2] = W1[k * 3 + 2];
        W1p[k * 4 + 3] = b1[k];
    }
    for (int idx = t; idx < kCOut * kCMid; idx += 256) {
        const int c = idx >> 7;        // idx / 128
        const int k = idx & 127;
        W2t[k * kCOut + c] = W2[idx];
    }
}

// ---------------------------------------------------------------------------
// Fused dense pass over permuted positions (b,i), 1 point/thread:
//   j = perm[b,i]; gather x[b,j]; both cell ids; atomicMax(winner, i+1);
//   full MLP (weights via uniform s_load); store feat[b,i] as 16 bf16 (32B).
// Cell math uses __fmul_rn/__fadd_rn (no FMA contraction) so truncation
// boundaries match numpy's mul-then-add exactly.
// 100% lane utilization on the 2688-op MLP; scatter memory traffic hides
// under the VALU stream.
// ---------------------------------------------------------------------------
__global__ __launch_bounds__(256) void fused_scatter_mlp(
    const float* __restrict__ x,
    const int* __restrict__ perm,
    const float* __restrict__ W1p, const float* __restrict__ W2t,
    const float* __restrict__ b2,
    unsigned int* __restrict__ win32, unsigned int* __restrict__ win64,
    uint4* __restrict__ feat)          // 2 uint4 per point (16 bf16)
{
    const long gid = (long)blockIdx.x * 256 + threadIdx.x;  // over B*N
    const int b = (int)(gid >> kNLog);
    const int i = (int)(gid & (kN - 1));
    const int j = perm[gid];

    const float* xp = x + ((long)b * kN + j) * 3;
    const float v0 = xp[0], v1 = xp[1], v2 = xp[2];

    const int ix32 = (int)fminf(fmaxf(__fadd_rn(__fmul_rn(v0, 32.0f), 16.5f), 0.0f), 31.0f);
    const int iy32 = (int)fminf(fmaxf(__fadd_rn(__fmul_rn(v1, 32.0f), 16.5f), 0.0f), 31.0f);
    const int iz32 = (int)fminf(fmaxf(__fadd_rn(__fmul_rn(v2, 32.0f), 16.5f), 0.0f), 31.0f);
    const int ix64 = (int)fminf(fmaxf(__fadd_rn(__fmul_rn(v0, 64.0f), 32.5f), 0.0f), 63.0f);
    const int iy64 = (int)fminf(fmaxf(__fadd_rn(__fmul_rn(v1, 64.0f), 32.5f), 0.0f), 63.0f);
    const int iz64 = (int)fminf(fmaxf(__fadd_rn(__fmul_rn(v2, 64.0f), 32.5f), 0.0f), 63.0f);

    const unsigned int pri = (unsigned int)(i + 1);
    atomicMax(&win32[b * kCells32 + (ix32 * 32 + iy32) * 32 + iz32], pri);
    atomicMax(&win64[b * kCells64 + (ix64 * 64 + iy64) * 64 + iz64], pri);

    float acc[kCOut];
    #pragma unroll
    for (int c = 0; c < kCOut; ++c) acc[c] = 0.0f;

    const float4* __restrict__ w1v = (const float4*)W1p;
    const float4* __restrict__ w2v = (const float4*)W2t;

    #pragma unroll 4
    for (int k = 0; k < kCMid; ++k) {
        const float4 w1 = w1v[k];                        // uniform -> s_load
        const float h = fmaxf(fmaf(w1.x, v0, fmaf(w1.y, v1, fmaf(w1.z, v2, w1.w))), 0.0f);
        #pragma unroll
        for (int q = 0; q < 4; ++q) {
            const float4 wq = w2v[k * 4 + q];            // uniform -> s_load
            acc[4 * q + 0] = fmaf(wq.x, h, acc[4 * q + 0]);
            acc[4 * q + 1] = fmaf(wq.y, h, acc[4 * q + 1]);
            acc[4 * q + 2] = fmaf(wq.z, h, acc[4 * q + 2]);
            acc[4 * q + 3] = fmaf(wq.w, h, acc[4 * q + 3]);
        }
    }

    const float4 bq0 = ((const float4*)b2)[0];
    const float4 bq1 = ((const float4*)b2)[1];
    const float4 bq2 = ((const float4*)b2)[2];
    const float4 bq3 = ((const float4*)b2)[3];

    uint4 f0, f1;
    f0.x = packbf2(acc[0]  + bq0.x, acc[1]  + bq0.y);
    f0.y = packbf2(acc[2]  + bq0.z, acc[3]  + bq0.w);
    f0.z = packbf2(acc[4]  + bq1.x, acc[5]  + bq1.y);
    f0.w = packbf2(acc[6]  + bq1.z, acc[7]  + bq1.w);
    f1.x = packbf2(acc[8]  + bq2.x, acc[9]  + bq2.y);
    f1.y = packbf2(acc[10] + bq2.z, acc[11] + bq2.w);
    f1.z = packbf2(acc[12] + bq3.x, acc[13] + bq3.y);
    f1.w = packbf2(acc[14] + bq3.z, acc[15] + bq3.w);
    feat[gid * 2 + 0] = f0;
    feat[gid * 2 + 1] = f1;
}

// ---------------------------------------------------------------------------
// Per-cell gather (pure memory): read winner; if non-empty fetch its 32B
// bf16 feature record and expand to f32; write all 16 channels (zeros if
// empty) so the full output is rewritten deterministically each call.
// ---------------------------------------------------------------------------
template <int CLOG>
__global__ __launch_bounds__(256) void gather_cells(
    const unsigned int* __restrict__ win,
    const uint4* __restrict__ feat,
    float* __restrict__ out)
{
    constexpr int cells = 1 << CLOG;
    const long gid = (long)blockIdx.x * 256 + threadIdx.x;  // over B*cells
    const int b = (int)(gid >> CLOG);
    const int cell = (int)(gid & (cells - 1));
    const unsigned int w = win[gid];

    float v[kCOut];
    #pragma unroll
    for (int c = 0; c < kCOut; ++c) v[c] = 0.0f;

    if (w != 0u) {
        const long pidx = ((long)b << kNLog) + (long)(w - 1u);
        const uint4 f0 = feat[pidx * 2 + 0];
        const uint4 f1 = feat[pidx * 2 + 1];
        v[0]  = bf_lo(f0.x); v[1]  = bf_hi(f0.x);
        v[2]  = bf_lo(f0.y); v[3]  = bf_hi(f0.y);
        v[4]  = bf_lo(f0.z); v[5]  = bf_hi(f0.z);
        v[6]  = bf_lo(f0.w); v[7]  = bf_hi(f0.w);
        v[8]  = bf_lo(f1.x); v[9]  = bf_hi(f1.x);
        v[10] = bf_lo(f1.y); v[11] = bf_hi(f1.y);
        v[12] = bf_lo(f1.z); v[13] = bf_hi(f1.z);
        v[14] = bf_lo(f1.w); v[15] = bf_hi(f1.w);
    }

    float* op = out + (((long)b * kCOut) << CLOG) + cell;
    #pragma unroll
    for (int c = 0; c < kCOut; ++c) op[(long)c << CLOG] = v[c];
}

extern "C" void kernel_launch(void* const* d_in, const int* in_sizes, int n_in,
                              void* d_out, int out_size, void* d_ws, size_t ws_size,
                              hipStream_t stream)
{
    const float* x  = (const float*)d_in[0];
    const float* W1 = (const float*)d_in[1];
    const float* b1 = (const float*)d_in[2];
    const float* W2 = (const float*)d_in[3];
    const float* b2 = (const float*)d_in[4];
    const int* perm = (const int*)d_in[5];

    float* out32 = (float*)d_out;
    float* out64 = out32 + kOut32Elems;

    // ws layout: [W1p 2KB][W2t 8KB][pad->16KB][win32 2MB][win64 16.8MB][feat 67MB]
    float* W1p = (float*)d_ws;
    float* W2t = W1p + kCMid * 4;
    unsigned int* win32 = (unsigned int*)((char*)d_ws + 16384);
    unsigned int* win64 = win32 + (size_t)kB * kCells32;
    const size_t winnerBytes = (size_t)kB * (kCells32 + kCells64) * sizeof(unsigned int);
    uint4* feat = (uint4*)((char*)win32 + winnerBytes);

    hipMemsetAsync(win32, 0, winnerBytes, stream);
    pack_weights<<<1, 256, 0, stream>>>(W1, b1, W2, W1p, W2t);

    const int nPtsBlocks = (int)(((long)kB * kN) / 256);        // 8192
    const int n32Blocks  = (int)(((long)kB * kCells32) / 256);  // 2048
    const int n64Blocks  = (int)(((long)kB * kCells64) / 256);  // 16384
    dim3 blk(256);

    fused_scatter_mlp<<<nPtsBlocks, blk, 0, stream>>>(
        x, perm, W1p, W2t, b2, win32, win64, feat);
    gather_cells<kCells32Log><<<n32Blocks, blk, 0, stream>>>(win32, feat, out32);
    gather_cells<kCells64Log><<<n64Blocks, blk, 0, stream>>>(win64, feat, out64);
}